// Round 14
// baseline (43.102 us; speedup 1.0000x reference)
//
#include <hip/hip_runtime.h>
#include <math.h>

#define BATCH 4
#define NPTS  8000
#define NCH   256
#define GDIM  20            // 20^3 = 8000 cells, ~1 point/cell
#define NCELL (GDIM*GDIM*GDIM)
#define CELLH (1.0f/GDIM)
#define EPS   1e-5f

// ---------- CAP-bucket layout (preferred; needs ~2.73 MB ws) ----------
#define CAPN  5
#define SPCAP 512
#define WS2_CNT   0          // [B][8000] int counts + [4] spillcnt right after
#define WS2_SPILL 131072     // [B][SPCAP] float4
#define WS2_PTS   163840     // [B][8000][CAPN] float4
#define WS2_TOTAL (163840 + (size_t)BATCH * NCELL * CAPN * 16)  // 2,723,840

// ---------- fallback layout (R12; needs 643,072 B) ----------
#define STRIDE_ST (NCELL + 16)
#define WS_STARTS 0
#define WS_PSORT  131072
#define WS_FB_TOTAL 643072

__device__ __forceinline__ int cell_clamp(float v) {
  int c = (int)(v * (float)GDIM);
  return c < 0 ? 0 : (c > GDIM - 1 ? GDIM - 1 : c);
}

// ==================== CAP path ====================

__global__ void zero_cnt_kernel(int* __restrict__ cnt) {
  const int g = blockIdx.x * 256 + threadIdx.x;
  if (g < BATCH * NCELL + BATCH) cnt[g] = 0;  // counts + spillcnt tail
}

// Fully parallel build: 1 point/thread, 1 global atomicAdd + 1 16B store.
__global__ void build_cap_kernel(const float* __restrict__ points,
                                 int* __restrict__ cnt,
                                 float4* __restrict__ cell_pts,
                                 float4* __restrict__ spill) {
  const int g = blockIdx.x * 256 + threadIdx.x;
  if (g >= BATCH * NPTS) return;
  const int b = g / NPTS;
  const int j = g - b * NPTS;
  const float* p = points + (size_t)b * NPTS * 3 + (size_t)j * 3;
  const float x = p[0], y = p[1], z = p[2];
  const int cid = (cell_clamp(z) * GDIM + cell_clamp(y)) * GDIM + cell_clamp(x);
  const float4 rec = make_float4(x, y, z, __int_as_float(j));
  const int pos = atomicAdd(&cnt[b * NCELL + cid], 1);
  if (pos < CAPN) {
    cell_pts[((size_t)b * NCELL + cid) * CAPN + pos] = rec;
  } else {
    int* spc = cnt + BATCH * NCELL;  // spillcnt[4] lives after counts
    const int sp = atomicAdd(&spc[b], 1);
    if (sp < SPCAP) spill[b * SPCAP + sp] = rec;  // P(overflow) ~ 0
  }
}

// candidate compare: key (max(d2,0), j) lexicographic; self skipped via j!=i
#define CAP_CAND(P)                                               \
  {                                                               \
    const float dot = xi * (P).x + yi * (P).y + zi * (P).z;       \
    const float sqj = (P).x * (P).x + (P).y * (P).y + (P).z * (P).z; \
    const float d2 = fmaxf((sqi + sqj) - 2.0f * dot, 0.0f);       \
    const int j = __float_as_int((P).w);                          \
    const bool lt = (j != i) &&                                   \
        ((d2 < b0) || (d2 == b0 && j < j0));                      \
    b0 = lt ? d2 : b0;                                            \
    j0 = lt ? j : j0;                                             \
  }

#define CAP_SCAN_CELL(CID)                                        \
  {                                                               \
    int n = cntb[(CID)];                                          \
    n = n < CAPN ? n : CAPN;                                      \
    const float4* base = cpb + (size_t)(CID) * CAPN;              \
    for (int slot = 0; slot < n; ++slot) {                        \
      const float4 P = base[slot];                                \
      CAP_CAND(P)                                                 \
    }                                                             \
  }

#define MERGE_XOR(MASK)                                           \
  {                                                               \
    const float ob = __shfl_xor(mb0, MASK);                       \
    const int oj = __shfl_xor(mj0, MASK);                         \
    const bool keep = (mb0 < ob) || (mb0 == ob && mj0 < oj);      \
    mb0 = keep ? mb0 : ob;                                        \
    mj0 = keep ? mj0 : oj;                                        \
  }

// Fused search+gather on CAP buckets, queries in ORIGINAL order (va/out
// rows block-sequential). Zero LDS / zero barriers. 16 lanes/query.
// Stage 1: 3^3 box + full spill; bound h^2. Stage 2: 5^3 box; bound (2h)^2.
// Stage 3: shells r>=3 (rare). Spill is scanned in FULL during stage 1, so
// bucket truncation never hides a candidate from any stage.
__global__ __launch_bounds__(256, 8) void search_gather_cap_kernel(
    const float* __restrict__ points, const int* __restrict__ cnt,
    const float4* __restrict__ cell_pts, const float4* __restrict__ spill,
    const float* __restrict__ preds, float* __restrict__ out) {
  const int t = threadIdx.x;
  const int b = blockIdx.y;
  const int ql = t >> 4;
  const int s = t & 15;
  const int i = blockIdx.x * 16 + ql;  // original index; 500*16 == 8000
  const float* pb = points + (size_t)b * NPTS * 3;
  const float xi = pb[i * 3 + 0];
  const float yi = pb[i * 3 + 1];
  const float zi = pb[i * 3 + 2];
  const float sqi = xi * xi + yi * yi + zi * zi;  // same expr as reference
  const int cx = cell_clamp(xi), cy = cell_clamp(yi), cz = cell_clamp(zi);
  const int* cntb = cnt + b * NCELL;
  const float4* cpb = cell_pts + (size_t)b * NCELL * CAPN;

  float b0 = INFINITY;
  int j0 = -1;

  // ---- stage 1: 3^3 box (27 cells; lane s -> cells s, s+16) + spill ----
  {
    const int c = s;
    const int dz = c / 9 - 1;
    const int rem = c % 9;
    const int z = cz + dz, y = cy + rem / 3 - 1, x = cx + rem % 3 - 1;
    if ((unsigned)z < GDIM && (unsigned)y < GDIM && (unsigned)x < GDIM) {
      const int cid = (z * GDIM + y) * GDIM + x;
      CAP_SCAN_CELL(cid)
    }
  }
  if (s < 11) {
    const int c = s + 16;
    const int dz = c / 9 - 1;
    const int rem = c % 9;
    const int z = cz + dz, y = cy + rem / 3 - 1, x = cx + rem % 3 - 1;
    if ((unsigned)z < GDIM && (unsigned)y < GDIM && (unsigned)x < GDIM) {
      const int cid = (z * GDIM + y) * GDIM + x;
      CAP_SCAN_CELL(cid)
    }
  }
  {
    const int spn = cnt[BATCH * NCELL + b];  // spillcnt
    const float4* spb = spill + b * SPCAP;
    for (int u = s; u < spn; u += 16) {
      const float4 P = spb[u];
      CAP_CAND(P)
    }
  }

  float mb0 = b0;
  int mj0 = j0;
  MERGE_XOR(1) MERGE_XOR(2) MERGE_XOR(4) MERGE_XOR(8)

  if (!(mb0 + EPS <= CELLH * CELLH)) {
    // ---- stage 2: full 5^3 box, 125 cells; lane s -> cells s+16k ----
#pragma unroll
    for (int k = 0; k < 8; ++k) {
      const int c = s + k * 16;
      if (c < 125) {
        const int dz = c / 25 - 2;
        const int rem = c % 25;
        const int z = cz + dz, y = cy + rem / 5 - 2, x = cx + rem % 5 - 2;
        if ((unsigned)z < GDIM && (unsigned)y < GDIM && (unsigned)x < GDIM) {
          const int cid = (z * GDIM + y) * GDIM + x;
          CAP_SCAN_CELL(cid)
        }
      }
    }
    mb0 = b0; mj0 = j0;
    MERGE_XOR(1) MERGE_XOR(2) MERGE_XOR(4) MERGE_XOR(8)

    if (!(mb0 + EPS <= (2.0f * CELLH) * (2.0f * CELLH))) {
      // ---- stage 3: Chebyshev shells r>=3, cell-by-cell (rare) ----
      for (int r = 3; r <= GDIM; ++r) {
        const int W = 2 * r + 1;
        for (int idx = s; idx < W * W; idx += 16) {
          const int dz = idx / W - r;
          const int dy = idx % W - r;
          const int z = cz + dz, y = cy + dy;
          if ((unsigned)z >= GDIM || (unsigned)y >= GDIM) continue;
          const int rowbase = (z * GDIM + y) * GDIM;
          if (dz == -r || dz == r || dy == -r || dy == r) {
            const int xl = cx > r ? cx - r : 0;
            const int xh = cx < GDIM - 1 - r ? cx + r : GDIM - 1;
            for (int x = xl; x <= xh; ++x) CAP_SCAN_CELL(rowbase + x)
          } else {
            if (cx - r >= 0) CAP_SCAN_CELL(rowbase + cx - r)
            if (cx + r <= GDIM - 1) CAP_SCAN_CELL(rowbase + cx + r)
          }
        }
        mb0 = b0; mj0 = j0;
        MERGE_XOR(1) MERGE_XOR(2) MERGE_XOR(4) MERGE_XOR(8)
        const float rb = (float)r * CELLH;
        if (mb0 + EPS <= rb * rb) break;
      }
    }
  }

  // ---- epilogue: wave w owns queries 4w..4w+3 (block-sequential rows) ----
  // Query ql lives in wave ql>>2 at wave-lanes (ql&3)*16..+15, so within
  // this wave, query (wv*4+k)'s merged result is at wave-lane k*16.
  const int wv = t >> 6;
  const int lane = t & 63;
  const float* predb = preds + (size_t)b * NPTS * NCH;
  float* outb = out + (size_t)b * NPTS * NCH;
#pragma unroll
  for (int k = 0; k < 4; ++k) {
    const int c = __shfl(mj0, k * 16);  // R13 bug: expression evaluated to k*32
    const int qo = blockIdx.x * 16 + wv * 4 + k;
    const float4 va = ((const float4*)(predb + (size_t)qo * NCH))[lane];
    const float4 vc = ((const float4*)(predb + (size_t)c * NCH))[lane];
    float4 r;
    r.x = 0.5f * (va.x + vc.x);
    r.y = 0.5f * (va.y + vc.y);
    r.z = 0.5f * (va.z + vc.z);
    r.w = 0.5f * (va.w + vc.w);
    ((float4*)(outb + (size_t)qo * NCH))[lane] = r;
  }
}

// ==================== fallback path (R12, verbatim) ====================

__global__ __launch_bounds__(1024) void build_kernel(const float* __restrict__ points,
                                                     int* __restrict__ starts,
                                                     float4* __restrict__ psort) {
  __shared__ int lst[NCELL];
  __shared__ int wtot[16];
  const int t = threadIdx.x;
  const int b = blockIdx.x;
  if (t < 1000) {
#pragma unroll
    for (int k = 0; k < 8; ++k) lst[t * 8 + k] = 0;
  }
  __syncthreads();

  const float* pb = points + (size_t)b * NPTS * 3;
  float px[8], py[8], pz[8];
  int pc[8];
  if (t < 1000) {
    const float4* pv = (const float4*)pb;
    const float4 a0 = pv[t * 6 + 0], a1 = pv[t * 6 + 1], a2 = pv[t * 6 + 2];
    const float4 a3 = pv[t * 6 + 3], a4 = pv[t * 6 + 4], a5 = pv[t * 6 + 5];
    px[0] = a0.x; py[0] = a0.y; pz[0] = a0.z;
    px[1] = a0.w; py[1] = a1.x; pz[1] = a1.y;
    px[2] = a1.z; py[2] = a1.w; pz[2] = a2.x;
    px[3] = a2.y; py[3] = a2.z; pz[3] = a2.w;
    px[4] = a3.x; py[4] = a3.y; pz[4] = a3.z;
    px[5] = a3.w; py[5] = a4.x; pz[5] = a4.y;
    px[6] = a4.z; py[6] = a4.w; pz[6] = a5.x;
    px[7] = a5.y; py[7] = a5.z; pz[7] = a5.w;
#pragma unroll
    for (int k = 0; k < 8; ++k) {
      pc[k] = (cell_clamp(pz[k]) * GDIM + cell_clamp(py[k])) * GDIM + cell_clamp(px[k]);
      atomicAdd(&lst[pc[k]], 1);
    }
  }
  __syncthreads();

  int v[8];
  int sum = 0;
  if (t < 1000) {
#pragma unroll
    for (int k = 0; k < 8; ++k) {
      v[k] = lst[t * 8 + k];
      sum += v[k];
    }
  }
  const int lane = t & 63, wv = t >> 6;
  int incl = sum;
#pragma unroll
  for (int d = 1; d < 64; d <<= 1) {
    const int u = __shfl_up(incl, d);
    if (lane >= d) incl += u;
  }
  if (lane == 63) wtot[wv] = incl;
  __syncthreads();
  if (wv == 0) {
    int x = (lane < 16) ? wtot[lane] : 0;
#pragma unroll
    for (int d = 1; d < 16; d <<= 1) {
      const int u = __shfl_up(x, d);
      if (lane >= d) x += u;
    }
    if (lane < 16) wtot[lane] = x;
  }
  __syncthreads();
  const int base = incl - sum + (wv ? wtot[wv - 1] : 0);

  int* stg = starts + b * STRIDE_ST;
  if (t < 1000) {
    int run = base;
#pragma unroll
    for (int k = 0; k < 8; ++k) {
      stg[t * 8 + k] = run;
      lst[t * 8 + k] = run;
      run += v[k];
    }
  }
  if (t == 0) stg[NCELL] = NPTS;
  __syncthreads();

  float4* psb = psort + (size_t)b * NPTS;
  if (t < 1000) {
#pragma unroll
    for (int k = 0; k < 8; ++k) {
      const int pos = atomicAdd(&lst[pc[k]], 1);
      psb[pos] = make_float4(px[k], py[k], pz[k], __int_as_float(t * 8 + k));
    }
  }
}

#define SCAN_RANGE(P0, P1)                                        \
  for (int p = (P0); p < (P1); ++p) {                             \
    const float4 P = ps[p];                                       \
    const float dot = xi * P.x + yi * P.y + zi * P.z;             \
    const float sqj = P.x * P.x + P.y * P.y + P.z * P.z;          \
    const float d2 = fmaxf((sqi + sqj) - 2.0f * dot, 0.0f);       \
    const int j = __float_as_int(P.w);                            \
    const bool lt = (p != i) &&                                   \
        ((d2 < b0) || (d2 == b0 && j < j0));                      \
    b0 = lt ? d2 : b0;                                            \
    j0 = lt ? j : j0;                                             \
  }

__global__ __launch_bounds__(256, 8) void search_gather_kernel(
    const float4* __restrict__ psort, const int* __restrict__ starts,
    const float* __restrict__ preds, float* __restrict__ out) {
  const int t = threadIdx.x;
  const int b = blockIdx.y;
  const int ql = t >> 4;
  const int s = t & 15;
  const int i = blockIdx.x * 16 + ql;
  const int* stg = starts + b * STRIDE_ST;
  const float4* ps = psort + (size_t)b * NPTS;
  const float4 Q = ps[i];
  const float xi = Q.x, yi = Q.y, zi = Q.z;
  const int qorig = __float_as_int(Q.w);
  const float sqi = xi * xi + yi * yi + zi * zi;
  const int cx = cell_clamp(xi), cy = cell_clamp(yi), cz = cell_clamp(zi);

  float b0 = INFINITY;
  int j0 = -1;

  {
    int lo0 = 0, hi0 = 0, lo1 = 0, hi1 = 0;
    {
      const int c = s;
      const int dz = c / 9 - 1;
      const int rem = c % 9;
      const int z = cz + dz, y = cy + rem / 3 - 1, x = cx + rem % 3 - 1;
      if ((unsigned)z < GDIM && (unsigned)y < GDIM && (unsigned)x < GDIM) {
        const int cid = (z * GDIM + y) * GDIM + x;
        lo0 = stg[cid];
        hi0 = stg[cid + 1];
      }
    }
    if (s < 11) {
      const int c = s + 16;
      const int dz = c / 9 - 1;
      const int rem = c % 9;
      const int z = cz + dz, y = cy + rem / 3 - 1, x = cx + rem % 3 - 1;
      if ((unsigned)z < GDIM && (unsigned)y < GDIM && (unsigned)x < GDIM) {
        const int cid = (z * GDIM + y) * GDIM + x;
        lo1 = stg[cid];
        hi1 = stg[cid + 1];
      }
    }
    SCAN_RANGE(lo0, hi0)
    SCAN_RANGE(lo1, hi1)
  }

  float mb0 = b0;
  int mj0 = j0;
  MERGE_XOR(1) MERGE_XOR(2) MERGE_XOR(4) MERGE_XOR(8)

  if (!(mb0 + EPS <= CELLH * CELLH)) {
    const int x0c = cx > 1 ? cx - 2 : 0;
    const int x1c = cx < GDIM - 2 ? cx + 2 : GDIM - 1;
    int rs[2], re[2];
#pragma unroll
    for (int rr = 0; rr < 2; ++rr) {
      const int kk = s + rr * 16;
      int lo = 0, hi = 0;
      if (kk < 25) {
        const int z = cz + kk / 5 - 2;
        const int y = cy + kk % 5 - 2;
        if ((unsigned)z < GDIM && (unsigned)y < GDIM) {
          const int rowbase = (z * GDIM + y) * GDIM;
          lo = stg[rowbase + x0c];
          hi = stg[rowbase + x1c + 1];
        }
      }
      rs[rr] = lo;
      re[rr] = hi;
    }
#pragma unroll
    for (int rr = 0; rr < 2; ++rr) { SCAN_RANGE(rs[rr], re[rr]) }

    mb0 = b0; mj0 = j0;
    MERGE_XOR(1) MERGE_XOR(2) MERGE_XOR(4) MERGE_XOR(8)

    if (!(mb0 + EPS <= (2.0f * CELLH) * (2.0f * CELLH))) {
      for (int r = 3; r <= GDIM; ++r) {
        const int W = 2 * r + 1;
        for (int idx = s; idx < W * W; idx += 16) {
          const int dz = idx / W - r;
          const int dy = idx % W - r;
          const int z = cz + dz, y = cy + dy;
          if ((unsigned)z >= GDIM || (unsigned)y >= GDIM) continue;
          const int rowbase = (z * GDIM + y) * GDIM;
          if (dz == -r || dz == r || dy == -r || dy == r) {
            const int xl = cx > r ? cx - r : 0;
            const int xh = cx < GDIM - 1 - r ? cx + r : GDIM - 1;
            const int lo = stg[rowbase + xl], hi = stg[rowbase + xh + 1];
            SCAN_RANGE(lo, hi)
          } else {
            if (cx - r >= 0) {
              const int lo = stg[rowbase + cx - r], hi = stg[rowbase + cx - r + 1];
              SCAN_RANGE(lo, hi)
            }
            if (cx + r <= GDIM - 1) {
              const int lo = stg[rowbase + cx + r], hi = stg[rowbase + cx + r + 1];
              SCAN_RANGE(lo, hi)
            }
          }
        }
        mb0 = b0; mj0 = j0;
        MERGE_XOR(1) MERGE_XOR(2) MERGE_XOR(4) MERGE_XOR(8)
        const float rb = (float)r * CELLH;
        if (mb0 + EPS <= rb * rb) break;
      }
    }
  }

  const int lane = t & 63;
  const float* predb = preds + (size_t)b * NPTS * NCH;
  float* outb = out + (size_t)b * NPTS * NCH;
#pragma unroll
  for (int k = 0; k < 4; ++k) {
    const int c = __shfl(mj0, k * 16);
    const int qo = __shfl(qorig, k * 16);
    const float4 va = ((const float4*)(predb + (size_t)qo * NCH))[lane];
    const float4 vc = ((const float4*)(predb + (size_t)c * NCH))[lane];
    float4 r;
    r.x = 0.5f * (va.x + vc.x);
    r.y = 0.5f * (va.y + vc.y);
    r.z = 0.5f * (va.z + vc.z);
    r.w = 0.5f * (va.w + vc.w);
    ((float4*)(outb + (size_t)qo * NCH))[lane] = r;
  }
}

extern "C" void kernel_launch(void* const* d_in, const int* in_sizes, int n_in,
                              void* d_out, int out_size, void* d_ws, size_t ws_size,
                              hipStream_t stream) {
  const float* points = (const float*)d_in[0];
  const float* preds = (const float*)d_in[1];
  // d_in[2] (k_vector) unused: reference hardcodes k = 2.
  float* out = (float*)d_out;
  char* ws = (char*)d_ws;

  if (ws_size >= WS2_TOTAL) {
    // ---- CAP-bucket path: parallel scan-free build ----
    int* cnt = (int*)(ws + WS2_CNT);
    float4* spill = (float4*)(ws + WS2_SPILL);
    float4* cell_pts = (float4*)(ws + WS2_PTS);
    const int nz = BATCH * NCELL + BATCH;
    zero_cnt_kernel<<<(nz + 255) / 256, 256, 0, stream>>>(cnt);
    build_cap_kernel<<<(BATCH * NPTS + 255) / 256, 256, 0, stream>>>(points, cnt, cell_pts, spill);
    search_gather_cap_kernel<<<dim3(NPTS / 16, BATCH), 256, 0, stream>>>(
        points, cnt, cell_pts, spill, preds, out);
  } else {
    // ---- fallback: R12 counting-sort path ----
    int* starts = (int*)(ws + WS_STARTS);
    float4* psort = (float4*)(ws + WS_PSORT);
    build_kernel<<<BATCH, 1024, 0, stream>>>(points, starts, psort);
    search_gather_kernel<<<dim3(NPTS / 16, BATCH), 256, 0, stream>>>(psort, starts, preds, out);
  }
}

// Round 16
// 34.529 us; speedup vs baseline: 1.2483x; 1.2483x over previous
//
#include <hip/hip_runtime.h>
#include <math.h>

#define BATCH 4
#define NPTS  8000
#define NCH   256
#define GDIM  20            // 20^3 = 8000 cells, ~1 point/cell
#define NCELL (GDIM*GDIM*GDIM)
#define CELLH (1.0f/GDIM)
#define EPS   1e-5f

// ws layout (bytes):
//   starts : [B][NCELL+16] int @ 0       (128256, rounded to 131072)
//   psort  : [B][NPTS] float4  @ 131072  (512000) (x,y,z, bitcast(orig j))
// total: 643072 bytes
#define STRIDE_ST (NCELL + 16)
#define WS_STARTS 0
#define WS_PSORT  131072

typedef float floatx4 __attribute__((ext_vector_type(4)));  // native clang vec

__device__ __forceinline__ int cell_clamp(float v) {
  int c = (int)(v * (float)GDIM);
  return c < 0 ? 0 : (c > GDIM - 1 ? GDIM - 1 : c);
}

// One block per batch: LDS histogram -> shuffle-scan (3 barriers) -> global
// starts (+ sentinel) + scatter into psort via LDS cursors.
// Thread t handles points [t*8, t*8+8) loaded as 6 float4 (96B contiguous);
// threads 0..999 also own cells [t*8, t*8+8) for histogram/scan.
__global__ __launch_bounds__(1024) void build_kernel(const float* __restrict__ points,
                                                     int* __restrict__ starts,
                                                     float4* __restrict__ psort) {
  __shared__ int lst[NCELL];
  __shared__ int wtot[16];
  const int t = threadIdx.x;
  const int b = blockIdx.x;
  if (t < 1000) {
#pragma unroll
    for (int k = 0; k < 8; ++k) lst[t * 8 + k] = 0;
  }
  __syncthreads();

  const float* pb = points + (size_t)b * NPTS * 3;
  float px[8], py[8], pz[8];
  int pc[8];
  if (t < 1000) {
    const float4* pv = (const float4*)pb;  // 6000 float4s per batch
    const float4 a0 = pv[t * 6 + 0], a1 = pv[t * 6 + 1], a2 = pv[t * 6 + 2];
    const float4 a3 = pv[t * 6 + 3], a4 = pv[t * 6 + 4], a5 = pv[t * 6 + 5];
    px[0] = a0.x; py[0] = a0.y; pz[0] = a0.z;
    px[1] = a0.w; py[1] = a1.x; pz[1] = a1.y;
    px[2] = a1.z; py[2] = a1.w; pz[2] = a2.x;
    px[3] = a2.y; py[3] = a2.z; pz[3] = a2.w;
    px[4] = a3.x; py[4] = a3.y; pz[4] = a3.z;
    px[5] = a3.w; py[5] = a4.x; pz[5] = a4.y;
    px[6] = a4.z; py[6] = a4.w; pz[6] = a5.x;
    px[7] = a5.y; py[7] = a5.z; pz[7] = a5.w;
#pragma unroll
    for (int k = 0; k < 8; ++k) {
      pc[k] = (cell_clamp(pz[k]) * GDIM + cell_clamp(py[k])) * GDIM + cell_clamp(px[k]);
      atomicAdd(&lst[pc[k]], 1);
    }
  }
  __syncthreads();

  // per-thread sum of its 8 cells, then wave scan + 16-wave-total scan
  int v[8];
  int sum = 0;
  if (t < 1000) {
#pragma unroll
    for (int k = 0; k < 8; ++k) {
      v[k] = lst[t * 8 + k];
      sum += v[k];
    }
  }
  const int lane = t & 63, wv = t >> 6;
  int incl = sum;
#pragma unroll
  for (int d = 1; d < 64; d <<= 1) {
    const int u = __shfl_up(incl, d);
    if (lane >= d) incl += u;
  }
  if (lane == 63) wtot[wv] = incl;
  __syncthreads();
  if (wv == 0) {
    int x = (lane < 16) ? wtot[lane] : 0;
#pragma unroll
    for (int d = 1; d < 16; d <<= 1) {
      const int u = __shfl_up(x, d);
      if (lane >= d) x += u;
    }
    if (lane < 16) wtot[lane] = x;
  }
  __syncthreads();
  const int base = incl - sum + (wv ? wtot[wv - 1] : 0);

  int* stg = starts + b * STRIDE_ST;
  if (t < 1000) {
    int run = base;
#pragma unroll
    for (int k = 0; k < 8; ++k) {
      stg[t * 8 + k] = run;
      lst[t * 8 + k] = run;  // own cells only: no race
      run += v[k];
    }
  }
  if (t == 0) stg[NCELL] = NPTS;  // sentinel: end of last cell
  __syncthreads();

  // scatter (LDS cursors); psort.w carries bitcast original index
  float4* psb = psort + (size_t)b * NPTS;
  if (t < 1000) {
#pragma unroll
    for (int k = 0; k < 8; ++k) {
      const int pos = atomicAdd(&lst[pc[k]], 1);
      psb[pos] = make_float4(px[k], py[k], pz[k], __int_as_float(t * 8 + k));
    }
  }
}

// Top-1-OTHER accumulation; key (max(d2,0), j) lexicographic == reference
// sort key + stable tie-break; self skipped via p != i in the compare.
// ONE 16B load per candidate (R9 lesson). Rescanning a range is idempotent
// (identical (d2,j) loses the strict compare) -> stage-2 full-box rescan ok.
#define SCAN_RANGE(P0, P1)                                        \
  for (int p = (P0); p < (P1); ++p) {                             \
    const float4 P = ps[p];                                       \
    const float dot = xi * P.x + yi * P.y + zi * P.z;             \
    const float sqj = P.x * P.x + P.y * P.y + P.z * P.z;          \
    const float d2 = fmaxf((sqi + sqj) - 2.0f * dot, 0.0f);       \
    const int j = __float_as_int(P.w);                            \
    const bool lt = (p != i) &&                                   \
        ((d2 < b0) || (d2 == b0 && j < j0));                      \
    b0 = lt ? d2 : b0;                                            \
    j0 = lt ? j : j0;                                             \
  }

#define MERGE_XOR(MASK)                                           \
  {                                                               \
    const float ob = __shfl_xor(mb0, MASK);                       \
    const int oj = __shfl_xor(mj0, MASK);                         \
    const bool keep = (mb0 < ob) || (mb0 == ob && mj0 < oj);      \
    mb0 = keep ? mb0 : ob;                                        \
    mj0 = keep ? mj0 : oj;                                        \
  }

// Fused NN search + gather/mean, ZERO LDS / ZERO barriers (R12 structure).
// 256 threads = 16 sorted-order queries x 16 lanes. Stage 1: 3^3 box ->
// bound h^2 (~97% stop). Stage 2: full 5^3 box as row-ranges -> (2h)^2.
// Stage 3 (~1e-3): Chebyshev shells r>=3. Epilogue: shfl broadcast within
// wave; OUT STORES NON-TEMPORAL (out is write-once -> don't evict preds
// from L2/L3; vc gather hit rate is the dominant memory term).
__global__ __launch_bounds__(256, 8) void search_gather_kernel(
    const float4* __restrict__ psort, const int* __restrict__ starts,
    const float* __restrict__ preds, float* __restrict__ out) {
  const int t = threadIdx.x;
  const int b = blockIdx.y;
  const int ql = t >> 4;  // 0..15
  const int s = t & 15;   // candidate split lane
  const int i = blockIdx.x * 16 + ql;  // 500*16 == 8000 exact
  const int* stg = starts + b * STRIDE_ST;
  const float4* ps = psort + (size_t)b * NPTS;
  const float4 Q = ps[i];
  const float xi = Q.x, yi = Q.y, zi = Q.z;
  const int qorig = __float_as_int(Q.w);
  const float sqi = xi * xi + yi * yi + zi * zi;  // same expr as reference
  const int cx = cell_clamp(xi), cy = cell_clamp(yi), cz = cell_clamp(zi);

  float b0 = INFINITY;
  int j0 = -1;

  // ---- stage 1: 3^3 box, 27 cells; lane s takes cells s and s+16 ----
  {
    int lo0 = 0, hi0 = 0, lo1 = 0, hi1 = 0;
    {
      const int c = s;  // 0..15, all < 27
      const int dz = c / 9 - 1;
      const int rem = c % 9;
      const int z = cz + dz, y = cy + rem / 3 - 1, x = cx + rem % 3 - 1;
      if ((unsigned)z < GDIM && (unsigned)y < GDIM && (unsigned)x < GDIM) {
        const int cid = (z * GDIM + y) * GDIM + x;
        lo0 = stg[cid];
        hi0 = stg[cid + 1];
      }
    }
    if (s < 11) {  // cells 16..26
      const int c = s + 16;
      const int dz = c / 9 - 1;
      const int rem = c % 9;
      const int z = cz + dz, y = cy + rem / 3 - 1, x = cx + rem % 3 - 1;
      if ((unsigned)z < GDIM && (unsigned)y < GDIM && (unsigned)x < GDIM) {
        const int cid = (z * GDIM + y) * GDIM + x;
        lo1 = stg[cid];
        hi1 = stg[cid + 1];
      }
    }
    SCAN_RANGE(lo0, hi0)
    SCAN_RANGE(lo1, hi1)
  }

  float mb0 = b0;
  int mj0 = j0;
  MERGE_XOR(1) MERGE_XOR(2) MERGE_XOR(4) MERGE_XOR(8)

  if (!(mb0 + EPS <= CELLH * CELLH)) {
    // ---- stage 2: full 5^3 box as 25 row-ranges (rows s and s+16) ----
    const int x0c = cx > 1 ? cx - 2 : 0;
    const int x1c = cx < GDIM - 2 ? cx + 2 : GDIM - 1;
    int rs[2], re[2];
#pragma unroll
    for (int rr = 0; rr < 2; ++rr) {
      const int kk = s + rr * 16;
      int lo = 0, hi = 0;
      if (kk < 25) {
        const int z = cz + kk / 5 - 2;
        const int y = cy + kk % 5 - 2;
        if ((unsigned)z < GDIM && (unsigned)y < GDIM) {
          const int rowbase = (z * GDIM + y) * GDIM;
          lo = stg[rowbase + x0c];
          hi = stg[rowbase + x1c + 1];  // sentinel covers == NCELL
        }
      }
      rs[rr] = lo;
      re[rr] = hi;
    }
#pragma unroll
    for (int rr = 0; rr < 2; ++rr) { SCAN_RANGE(rs[rr], re[rr]) }

    mb0 = b0; mj0 = j0;
    MERGE_XOR(1) MERGE_XOR(2) MERGE_XOR(4) MERGE_XOR(8)

    if (!(mb0 + EPS <= (2.0f * CELLH) * (2.0f * CELLH))) {
      // ---- stage 3: expanding Chebyshev shells r>=3, row-range form ----
      for (int r = 3; r <= GDIM; ++r) {
        const int W = 2 * r + 1;
        for (int idx = s; idx < W * W; idx += 16) {
          const int dz = idx / W - r;
          const int dy = idx % W - r;
          const int z = cz + dz, y = cy + dy;
          if ((unsigned)z >= GDIM || (unsigned)y >= GDIM) continue;
          const int rowbase = (z * GDIM + y) * GDIM;
          if (dz == -r || dz == r || dy == -r || dy == r) {
            const int xl = cx > r ? cx - r : 0;
            const int xh = cx < GDIM - 1 - r ? cx + r : GDIM - 1;
            const int lo = stg[rowbase + xl], hi = stg[rowbase + xh + 1];
            SCAN_RANGE(lo, hi)
          } else {
            if (cx - r >= 0) {
              const int lo = stg[rowbase + cx - r], hi = stg[rowbase + cx - r + 1];
              SCAN_RANGE(lo, hi)
            }
            if (cx + r <= GDIM - 1) {
              const int lo = stg[rowbase + cx + r], hi = stg[rowbase + cx + r + 1];
              SCAN_RANGE(lo, hi)
            }
          }
        }
        mb0 = b0; mj0 = j0;
        MERGE_XOR(1) MERGE_XOR(2) MERGE_XOR(4) MERGE_XOR(8)
        const float rb = (float)r * CELLH;
        if (mb0 + EPS <= rb * rb) break;
      }
    }
  }

  // ---- epilogue: wave w owns queries 4w..4w+3; shfl-broadcast, no LDS ----
  const int lane = t & 63;
  const float* predb = preds + (size_t)b * NPTS * NCH;
  float* outb = out + (size_t)b * NPTS * NCH;
#pragma unroll
  for (int k = 0; k < 4; ++k) {
    const int c = __shfl(mj0, k * 16);
    const int qo = __shfl(qorig, k * 16);
    const float4 va = ((const float4*)(predb + (size_t)qo * NCH))[lane];
    const float4 vc = ((const float4*)(predb + (size_t)c * NCH))[lane];
    floatx4 r;
    r.x = 0.5f * (va.x + vc.x);
    r.y = 0.5f * (va.y + vc.y);
    r.z = 0.5f * (va.z + vc.z);
    r.w = 0.5f * (va.w + vc.w);
    // write-once output: non-temporal 16B store (native clang vector type),
    // don't evict preds from L2/L3
    __builtin_nontemporal_store(r, (floatx4*)(outb + (size_t)qo * NCH) + lane);
  }
}

extern "C" void kernel_launch(void* const* d_in, const int* in_sizes, int n_in,
                              void* d_out, int out_size, void* d_ws, size_t ws_size,
                              hipStream_t stream) {
  const float* points = (const float*)d_in[0];
  const float* preds = (const float*)d_in[1];
  // d_in[2] (k_vector) unused: reference hardcodes k = 2.
  float* out = (float*)d_out;

  char* ws = (char*)d_ws;
  int* starts = (int*)(ws + WS_STARTS);
  float4* psort = (float4*)(ws + WS_PSORT);

  build_kernel<<<BATCH, 1024, 0, stream>>>(points, starts, psort);
  search_gather_kernel<<<dim3(NPTS / 16, BATCH), 256, 0, stream>>>(psort, starts, preds, out);
}

// Round 17
// 34.116 us; speedup vs baseline: 1.2634x; 1.0121x over previous
//
#include <hip/hip_runtime.h>
#include <math.h>

#define BATCH 4
#define NPTS  8000
#define NCH   256
#define GDIM  20            // 20^3 = 8000 cells, ~1 point/cell
#define NCELL (GDIM*GDIM*GDIM)
#define CELLH (1.0f/GDIM)
#define EPS   1e-5f

// ws layout (bytes):
//   starts : [B][NCELL+16] int @ 0       (128256, rounded to 131072)
//   psort  : [B][NPTS] float4  @ 131072  (512000) (x,y,z, bitcast(orig j))
// total: 643072 bytes
#define STRIDE_ST (NCELL + 16)
#define WS_STARTS 0
#define WS_PSORT  131072

typedef float floatx4 __attribute__((ext_vector_type(4)));  // native clang vec

__device__ __forceinline__ int cell_clamp(float v) {
  int c = (int)(v * (float)GDIM);
  return c < 0 ? 0 : (c > GDIM - 1 ? GDIM - 1 : c);
}

// One block per batch: LDS histogram -> shuffle-scan (3 barriers) -> global
// starts (+ sentinel) + scatter into psort via LDS cursors.
// Thread t handles points [t*8, t*8+8) loaded as 6 float4 (96B contiguous);
// threads 0..999 also own cells [t*8, t*8+8) for histogram/scan.
__global__ __launch_bounds__(1024) void build_kernel(const float* __restrict__ points,
                                                     int* __restrict__ starts,
                                                     float4* __restrict__ psort) {
  __shared__ int lst[NCELL];
  __shared__ int wtot[16];
  const int t = threadIdx.x;
  const int b = blockIdx.x;
  if (t < 1000) {
#pragma unroll
    for (int k = 0; k < 8; ++k) lst[t * 8 + k] = 0;
  }
  __syncthreads();

  const float* pb = points + (size_t)b * NPTS * 3;
  float px[8], py[8], pz[8];
  int pc[8];
  if (t < 1000) {
    const float4* pv = (const float4*)pb;  // 6000 float4s per batch
    const float4 a0 = pv[t * 6 + 0], a1 = pv[t * 6 + 1], a2 = pv[t * 6 + 2];
    const float4 a3 = pv[t * 6 + 3], a4 = pv[t * 6 + 4], a5 = pv[t * 6 + 5];
    px[0] = a0.x; py[0] = a0.y; pz[0] = a0.z;
    px[1] = a0.w; py[1] = a1.x; pz[1] = a1.y;
    px[2] = a1.z; py[2] = a1.w; pz[2] = a2.x;
    px[3] = a2.y; py[3] = a2.z; pz[3] = a2.w;
    px[4] = a3.x; py[4] = a3.y; pz[4] = a3.z;
    px[5] = a3.w; py[5] = a4.x; pz[5] = a4.y;
    px[6] = a4.z; py[6] = a4.w; pz[6] = a5.x;
    px[7] = a5.y; py[7] = a5.z; pz[7] = a5.w;
#pragma unroll
    for (int k = 0; k < 8; ++k) {
      pc[k] = (cell_clamp(pz[k]) * GDIM + cell_clamp(py[k])) * GDIM + cell_clamp(px[k]);
      atomicAdd(&lst[pc[k]], 1);
    }
  }
  __syncthreads();

  // per-thread sum of its 8 cells, then wave scan + 16-wave-total scan
  int v[8];
  int sum = 0;
  if (t < 1000) {
#pragma unroll
    for (int k = 0; k < 8; ++k) {
      v[k] = lst[t * 8 + k];
      sum += v[k];
    }
  }
  const int lane = t & 63, wv = t >> 6;
  int incl = sum;
#pragma unroll
  for (int d = 1; d < 64; d <<= 1) {
    const int u = __shfl_up(incl, d);
    if (lane >= d) incl += u;
  }
  if (lane == 63) wtot[wv] = incl;
  __syncthreads();
  if (wv == 0) {
    int x = (lane < 16) ? wtot[lane] : 0;
#pragma unroll
    for (int d = 1; d < 16; d <<= 1) {
      const int u = __shfl_up(x, d);
      if (lane >= d) x += u;
    }
    if (lane < 16) wtot[lane] = x;
  }
  __syncthreads();
  const int base = incl - sum + (wv ? wtot[wv - 1] : 0);

  int* stg = starts + b * STRIDE_ST;
  if (t < 1000) {
    int run = base;
#pragma unroll
    for (int k = 0; k < 8; ++k) {
      stg[t * 8 + k] = run;
      lst[t * 8 + k] = run;  // own cells only: no race
      run += v[k];
    }
  }
  if (t == 0) stg[NCELL] = NPTS;  // sentinel: end of last cell
  __syncthreads();

  // scatter (LDS cursors); psort.w carries bitcast original index
  float4* psb = psort + (size_t)b * NPTS;
  if (t < 1000) {
#pragma unroll
    for (int k = 0; k < 8; ++k) {
      const int pos = atomicAdd(&lst[pc[k]], 1);
      psb[pos] = make_float4(px[k], py[k], pz[k], __int_as_float(t * 8 + k));
    }
  }
}

// Top-1-OTHER accumulation; key (max(d2,0), j) lexicographic == reference
// sort key + stable tie-break; self skipped via p != i in the compare.
// ONE 16B load per candidate (R9 lesson). Rescanning a range is idempotent
// (identical (d2,j) loses the strict compare) -> stage-2 full-box rescan ok.
#define SCAN_RANGE(P0, P1)                                        \
  for (int p = (P0); p < (P1); ++p) {                             \
    const float4 P = ps[p];                                       \
    const float dot = xi * P.x + yi * P.y + zi * P.z;             \
    const float sqj = P.x * P.x + P.y * P.y + P.z * P.z;          \
    const float d2 = fmaxf((sqi + sqj) - 2.0f * dot, 0.0f);       \
    const int j = __float_as_int(P.w);                            \
    const bool lt = (p != i) &&                                   \
        ((d2 < b0) || (d2 == b0 && j < j0));                      \
    b0 = lt ? d2 : b0;                                            \
    j0 = lt ? j : j0;                                             \
  }

#define MERGE_XOR(MASK)                                           \
  {                                                               \
    const float ob = __shfl_xor(mb0, MASK);                       \
    const int oj = __shfl_xor(mj0, MASK);                         \
    const bool keep = (mb0 < ob) || (mb0 == ob && mj0 < oj);      \
    mb0 = keep ? mb0 : ob;                                        \
    mj0 = keep ? mj0 : oj;                                        \
  }

// Fused NN search + gather/mean, ZERO LDS / ZERO barriers (R12 structure).
// 256 threads = 16 sorted-order queries x 16 lanes. The 4 self-row (va)
// 1KB loads per wave are issued BEFORE the search (qorig known at start):
// ~33 MB of gather traffic hides under the latency-bound candidate scan.
// Stage 1: 3^3 box -> bound h^2 (~97% stop). Stage 2: 5^3 box row-ranges
// -> (2h)^2. Stage 3 (~1e-3): shells r>=3. Epilogue: batch 4 vc loads,
// then compute+NT-store (write-once out, don't pollute L2/L3).
__global__ __launch_bounds__(256, 8) void search_gather_kernel(
    const float4* __restrict__ psort, const int* __restrict__ starts,
    const float* __restrict__ preds, float* __restrict__ out) {
  const int t = threadIdx.x;
  const int b = blockIdx.y;
  const int ql = t >> 4;  // 0..15
  const int s = t & 15;   // candidate split lane
  const int i = blockIdx.x * 16 + ql;  // 500*16 == 8000 exact
  const int* stg = starts + b * STRIDE_ST;
  const float4* ps = psort + (size_t)b * NPTS;
  const float4 Q = ps[i];
  const float xi = Q.x, yi = Q.y, zi = Q.z;
  const int qorig = __float_as_int(Q.w);
  const float sqi = xi * xi + yi * yi + zi * zi;  // same expr as reference
  const int cx = cell_clamp(xi), cy = cell_clamp(yi), cz = cell_clamp(zi);

  // ---- va prefetch: all 4 qorig of this wave are known NOW ----
  const int lane = t & 63;
  const float* predb = preds + (size_t)b * NPTS * NCH;
  int qo[4];
  float4 va[4];
#pragma unroll
  for (int k = 0; k < 4; ++k) {
    qo[k] = __shfl(qorig, k * 16);
    va[k] = ((const float4*)(predb + (size_t)qo[k] * NCH))[lane];
  }

  float b0 = INFINITY;
  int j0 = -1;

  // ---- stage 1: 3^3 box, 27 cells; lane s takes cells s and s+16 ----
  {
    int lo0 = 0, hi0 = 0, lo1 = 0, hi1 = 0;
    {
      const int c = s;  // 0..15, all < 27
      const int dz = c / 9 - 1;
      const int rem = c % 9;
      const int z = cz + dz, y = cy + rem / 3 - 1, x = cx + rem % 3 - 1;
      if ((unsigned)z < GDIM && (unsigned)y < GDIM && (unsigned)x < GDIM) {
        const int cid = (z * GDIM + y) * GDIM + x;
        lo0 = stg[cid];
        hi0 = stg[cid + 1];
      }
    }
    if (s < 11) {  // cells 16..26
      const int c = s + 16;
      const int dz = c / 9 - 1;
      const int rem = c % 9;
      const int z = cz + dz, y = cy + rem / 3 - 1, x = cx + rem % 3 - 1;
      if ((unsigned)z < GDIM && (unsigned)y < GDIM && (unsigned)x < GDIM) {
        const int cid = (z * GDIM + y) * GDIM + x;
        lo1 = stg[cid];
        hi1 = stg[cid + 1];
      }
    }
    SCAN_RANGE(lo0, hi0)
    SCAN_RANGE(lo1, hi1)
  }

  float mb0 = b0;
  int mj0 = j0;
  MERGE_XOR(1) MERGE_XOR(2) MERGE_XOR(4) MERGE_XOR(8)

  if (!(mb0 + EPS <= CELLH * CELLH)) {
    // ---- stage 2: full 5^3 box as 25 row-ranges (rows s and s+16) ----
    const int x0c = cx > 1 ? cx - 2 : 0;
    const int x1c = cx < GDIM - 2 ? cx + 2 : GDIM - 1;
    int rs[2], re[2];
#pragma unroll
    for (int rr = 0; rr < 2; ++rr) {
      const int kk = s + rr * 16;
      int lo = 0, hi = 0;
      if (kk < 25) {
        const int z = cz + kk / 5 - 2;
        const int y = cy + kk % 5 - 2;
        if ((unsigned)z < GDIM && (unsigned)y < GDIM) {
          const int rowbase = (z * GDIM + y) * GDIM;
          lo = stg[rowbase + x0c];
          hi = stg[rowbase + x1c + 1];  // sentinel covers == NCELL
        }
      }
      rs[rr] = lo;
      re[rr] = hi;
    }
#pragma unroll
    for (int rr = 0; rr < 2; ++rr) { SCAN_RANGE(rs[rr], re[rr]) }

    mb0 = b0; mj0 = j0;
    MERGE_XOR(1) MERGE_XOR(2) MERGE_XOR(4) MERGE_XOR(8)

    if (!(mb0 + EPS <= (2.0f * CELLH) * (2.0f * CELLH))) {
      // ---- stage 3: expanding Chebyshev shells r>=3, row-range form ----
      for (int r = 3; r <= GDIM; ++r) {
        const int W = 2 * r + 1;
        for (int idx = s; idx < W * W; idx += 16) {
          const int dz = idx / W - r;
          const int dy = idx % W - r;
          const int z = cz + dz, y = cy + dy;
          if ((unsigned)z >= GDIM || (unsigned)y >= GDIM) continue;
          const int rowbase = (z * GDIM + y) * GDIM;
          if (dz == -r || dz == r || dy == -r || dy == r) {
            const int xl = cx > r ? cx - r : 0;
            const int xh = cx < GDIM - 1 - r ? cx + r : GDIM - 1;
            const int lo = stg[rowbase + xl], hi = stg[rowbase + xh + 1];
            SCAN_RANGE(lo, hi)
          } else {
            if (cx - r >= 0) {
              const int lo = stg[rowbase + cx - r], hi = stg[rowbase + cx - r + 1];
              SCAN_RANGE(lo, hi)
            }
            if (cx + r <= GDIM - 1) {
              const int lo = stg[rowbase + cx + r], hi = stg[rowbase + cx + r + 1];
              SCAN_RANGE(lo, hi)
            }
          }
        }
        mb0 = b0; mj0 = j0;
        MERGE_XOR(1) MERGE_XOR(2) MERGE_XOR(4) MERGE_XOR(8)
        const float rb = (float)r * CELLH;
        if (mb0 + EPS <= rb * rb) break;
      }
    }
  }

  // ---- epilogue: batch the 4 vc loads (4 in flight), then compute/store ----
  float* outb = out + (size_t)b * NPTS * NCH;
  float4 vc[4];
#pragma unroll
  for (int k = 0; k < 4; ++k) {
    const int c = __shfl(mj0, k * 16);
    vc[k] = ((const float4*)(predb + (size_t)c * NCH))[lane];
  }
#pragma unroll
  for (int k = 0; k < 4; ++k) {
    floatx4 r;
    r.x = 0.5f * (va[k].x + vc[k].x);
    r.y = 0.5f * (va[k].y + vc[k].y);
    r.z = 0.5f * (va[k].z + vc[k].z);
    r.w = 0.5f * (va[k].w + vc[k].w);
    // write-once output: non-temporal 16B store, don't evict preds from L2/L3
    __builtin_nontemporal_store(r, (floatx4*)(outb + (size_t)qo[k] * NCH) + lane);
  }
}

extern "C" void kernel_launch(void* const* d_in, const int* in_sizes, int n_in,
                              void* d_out, int out_size, void* d_ws, size_t ws_size,
                              hipStream_t stream) {
  const float* points = (const float*)d_in[0];
  const float* preds = (const float*)d_in[1];
  // d_in[2] (k_vector) unused: reference hardcodes k = 2.
  float* out = (float*)d_out;

  char* ws = (char*)d_ws;
  int* starts = (int*)(ws + WS_STARTS);
  float4* psort = (float4*)(ws + WS_PSORT);

  build_kernel<<<BATCH, 1024, 0, stream>>>(points, starts, psort);
  search_gather_kernel<<<dim3(NPTS / 16, BATCH), 256, 0, stream>>>(psort, starts, preds, out);
}